// Round 1
// baseline (36.420 us; speedup 1.0000x reference)
//
#include <hip/hip_runtime.h>
#include <math.h>

#define NSEG 30          // scan steps i = 0..29
#define QOFF 0           // Q table: 31 entries * 6 floats = 186
#define TOFF 192         // T table: 31 entries * 9 floats = 279
#define TABSZ 472        // padded total floats

// ---------------- tiny serial kernel: build per-segment control tables ----------------
__global__ void yuksel_build_tables(const float* __restrict__ P, float* __restrict__ tab) {
    if (threadIdx.x != 0 || blockIdx.x != 0) return;
    float Q[3][2], T[3][3];
    for (int r = 0; r < 3; ++r) {
        float a = P[r*5+2], b = P[r*5+3], c = P[r*5+4];
        Q[r][0] = P[r*5+0]; Q[r][1] = P[r*5+1];
        T[r][0] = a*a + b*b; T[r][1] = b*(a + c); T[r][2] = b*b + c*c;
    }
    float* Qt = tab + QOFF;
    float* Tt = tab + TOFF;
    for (int r = 0; r < 3; ++r) { Qt[2*r] = Q[r][0]; Qt[2*r+1] = Q[r][1]; }
    for (int r = 0; r < 3; ++r)
        for (int c2 = 0; c2 < 3; ++c2) Tt[3*r+c2] = T[r][c2];

    for (int i = 0; i < NSEG; ++i) {
        int nr = i + 3;
        float p2x = P[nr*5+0], p2y = P[nr*5+1];
        float a = P[nr*5+2], b = P[nr*5+3], c = P[nr*5+4];
        float s2[3] = { a*a + b*b, b*(a + c), b*b + c*c };

        float p0x = (Q[0][0] + Q[2][0]) * 0.25f + Q[1][0] * 0.5f;
        float p0y = (Q[0][1] + Q[2][1]) * 0.25f + Q[1][1] * 0.5f;
        float p1x = 2.0f * (Q[2][0] - (p0x + p2x) * 0.25f);
        float p1y = 2.0f * (Q[2][1] - (p0y + p2y) * 0.25f);
        Q[0][0] = p0x; Q[0][1] = p0y;
        Q[1][0] = p1x; Q[1][1] = p1y;
        Q[2][0] = p2x; Q[2][1] = p2y;

        float s0[3], s1[3];
        for (int c2 = 0; c2 < 3; ++c2) {
            s0[c2] = (T[0][c2] + T[2][c2]) * 0.0625f + T[1][c2] * 0.25f;
            s1[c2] = 4.0f * (T[2][c2] - (s0[c2] + s2[c2]) * 0.0625f);
        }
        for (int c2 = 0; c2 < 3; ++c2) {
            T[0][c2] = s0[c2]; T[1][c2] = s1[c2]; T[2][c2] = s2[c2];
        }

        float* q = Qt + (i + 1) * 6;
        for (int r = 0; r < 3; ++r) { q[2*r] = Q[r][0]; q[2*r+1] = Q[r][1]; }
        float* t = Tt + (i + 1) * 9;
        for (int r = 0; r < 3; ++r)
            for (int c2 = 0; c2 < 3; ++c2) t[3*r+c2] = T[r][c2];
    }
}

// ---------------- main map kernel: 4 points per thread ----------------
__global__ __launch_bounds__(256) void yuksel_eval(
    const float* __restrict__ x, const float* __restrict__ tab,
    float* __restrict__ out, int N)
{
    __shared__ float lt[TABSZ];
    for (int k = threadIdx.x; k < TABSZ; k += 256) lt[k] = tab[k];
    __syncthreads();
    const float* lQ = lt + QOFF;
    const float* lT = lt + TOFF;

    int gid = blockIdx.x * 256 + threadIdx.x;
    int j0 = gid * 4;
    if (j0 >= N) return;

    float4 xv = *reinterpret_cast<const float4*>(x + j0);
    float xs[4] = { xv.x, xv.y, xv.z, xv.w };
    float mu[8], sg[12];

#pragma unroll
    for (int q = 0; q < 4; ++q) {
        float u  = xs[q] * 30.0f;
        float fi = floorf(u);
        fi = fminf(fmaxf(fi, 0.0f), 29.0f);
        int   i  = (int)fi;
        float d  = (u - fi) * 0.5f;          // in [0, 0.5)
        float e  = d + 0.5f;

        // Bernstein basis at d (curr) and d+0.5 (prev)
        float omd = 1.0f - d;
        float bc0 = omd * omd, bc1 = 2.0f * d * omd, bc2 = d * d;
        float ome = 1.0f - e;
        float bp0 = ome * ome, bp1 = 2.0f * e * ome, bp2 = e * e;

        float cpi = cospif(d);
        float cw  = cpi * cpi;
        float sw  = 1.0f - cw;
        float cw2 = cw * cw, sw2 = sw * sw;

        const float* Qi = lQ + i * 6;    // Q_i (6) then Q_{i+1} (6)
        const float* Ti = lT + i * 9;    // T_i (9) then T_{i+1} (9)

        float fpx = bp0*Qi[0] + bp1*Qi[2] + bp2*Qi[4];
        float fpy = bp0*Qi[1] + bp1*Qi[3] + bp2*Qi[5];
        float fcx = bc0*Qi[6] + bc1*Qi[8] + bc2*Qi[10];
        float fcy = bc0*Qi[7] + bc1*Qi[9] + bc2*Qi[11];
        mu[2*q+0] = cw*fpx + sw*fcx;
        mu[2*q+1] = cw*fpy + sw*fcy;

        float a0 = bp0*bp0, a1 = bp1*bp1, a2 = bp2*bp2;
        float c0 = bc0*bc0, c1 = bc1*bc1, c2 = bc2*bc2;
        float gp0 = a0*Ti[0] + a1*Ti[3] + a2*Ti[6];
        float gp1 = a0*Ti[1] + a1*Ti[4] + a2*Ti[7];
        float gp2 = a0*Ti[2] + a1*Ti[5] + a2*Ti[8];
        float gc0 = c0*Ti[9]  + c1*Ti[12] + c2*Ti[15];
        float gc1 = c0*Ti[10] + c1*Ti[13] + c2*Ti[16];
        float gc2 = c0*Ti[11] + c1*Ti[14] + c2*Ti[17];
        sg[3*q+0] = cw2*gp0 + sw2*gc0;
        sg[3*q+1] = cw2*gp1 + sw2*gc1;
        sg[3*q+2] = cw2*gp2 + sw2*gc2;
    }

    // mu region: elements [2*j0, 2*j0+8) -> two aligned float4 stores
    float4* muOut = reinterpret_cast<float4*>(out + 2*j0);
    muOut[0] = make_float4(mu[0], mu[1], mu[2], mu[3]);
    muOut[1] = make_float4(mu[4], mu[5], mu[6], mu[7]);
    // sg region: elements [2N + 3*j0, +12) -> three aligned float4 stores
    float4* sgOut = reinterpret_cast<float4*>(out + (size_t)2*N + 3*j0);
    sgOut[0] = make_float4(sg[0], sg[1], sg[2],  sg[3]);
    sgOut[1] = make_float4(sg[4], sg[5], sg[6],  sg[7]);
    sgOut[2] = make_float4(sg[8], sg[9], sg[10], sg[11]);
}

extern "C" void kernel_launch(void* const* d_in, const int* in_sizes, int n_in,
                              void* d_out, int out_size, void* d_ws, size_t ws_size,
                              hipStream_t stream) {
    const float* x = (const float*)d_in[0];
    const float* P = (const float*)d_in[1];
    float* out = (float*)d_out;
    float* tab = (float*)d_ws;
    int N = in_sizes[0];

    yuksel_build_tables<<<1, 64, 0, stream>>>(P, tab);

    const int threads = 256;
    const int per_block = threads * 4;
    int blocks = (N + per_block - 1) / per_block;
    yuksel_eval<<<blocks, threads, 0, stream>>>(x, tab, out, N);
}